// Round 3
// baseline (536.757 us; speedup 1.0000x reference)
//
#include <hip/hip_runtime.h>

// ---------------------------------------------------------------------------
// QuantumQLSTM: analytic collapse of the quantum circuit.
//   ang[g][b][n] = W_g[n,:256]·x + W_g[n,256:264]·hx + bias_g[n] + theta_g[n]
//   m[g][b][0]   = prod_{j=1..7} cos(ang[g][b][j])
//   m[g][b][n>0] = prod_{j=0..n} cos(ang[g][b][j])
// then a standard LSTM cell update.
// ---------------------------------------------------------------------------

#define BQ   512   // batch
#define TT   512   // timesteps
#define IND  256   // input dim
#define PRE_OFF 8704  // float offset of pre[] inside ws

// ws float layout:
//   [0, 8192)        Wt[d][gn]   (256 x 32)  x-part of W, transposed
//   [8192, 8448)     Wh[gn][j]   (32 x 8)    h-part of W
//   [8448, 8480)     C[gn]                    bias + theta
//   [8704, 8704+8388608)  pre[b][t/4][gn][4]  (B*T*32 floats)

__global__ void prep_kernel(const float* __restrict__ Wf, const float* __restrict__ bf,
                            const float* __restrict__ Wi, const float* __restrict__ bi,
                            const float* __restrict__ Wg, const float* __restrict__ bg,
                            const float* __restrict__ Wo, const float* __restrict__ bo,
                            const float* __restrict__ th, float* __restrict__ wsf) {
    const float* W[4]    = {Wf, Wi, Wg, Wo};
    const float* bias[4] = {bf, bi, bg, bo};
    int d = threadIdx.x;  // 0..255
    for (int g = 0; g < 4; g++)
        for (int n = 0; n < 8; n++)
            wsf[d * 32 + g * 8 + n] = W[g][n * 264 + d];
    if (d < 32) {
        int g = d >> 3, n = d & 7;
        for (int j = 0; j < 8; j++)
            wsf[8192 + d * 8 + j] = W[g][n * 264 + 256 + j];
        wsf[8448 + d] = bias[g][n] + th[d];
    }
}

// ---------------------------------------------------------------------------
// pre_gemm v3: true software pipeline — loads in flight DURING compute.
//   v2 post-mortem: hipcc drains vmcnt(0) at every __syncthreads(), so the
//   prefetch issued before the barrier was waited out BEFORE compute began.
//   Per chunk: [issue 8 loads][stall ~HBM latency][compute 2048cy, 0 bytes in
//   flight] -> ~35% memory duty cycle -> effective 2.3 TB/s (matches v1&v2).
//   v3 uses the verified m201 pattern: raw __builtin_amdgcn_s_barrier() +
//   inline-asm counted waitcnt. Next-chunk global loads are issued before the
//   barrier and retire UNDER the 2048-cycle FMA phase; the vmcnt(0) at the
//   top of the next iteration is then ~free.
//   LDS tile [256][32] with rotation swizzle (k+row)&31 at 4B granule:
//     compute read (fixed k, row=tid varies): bank=(k+tid)%32 -> 2-way, free.
//     stage write (srow=tid>>3, sk4=tid&7):  bank=(4*sk4+j+srow)%32 -> 2-way.
//   32 KB LDS, no pad -> 4 blocks/CU (16 waves/CU) for cross-block overlap.
//   FMA order over k unchanged from v1/v2 -> bit-identical output.
// ---------------------------------------------------------------------------

#define ROWS 256   // bt rows per block (= threads)
#define KC   32    // K-chunk width
#define NCH  (IND / KC)   // 8 chunks

__global__ __launch_bounds__(256, 4) void pre_gemm(const float* __restrict__ x,
                                                   const float* __restrict__ wsf,
                                                   float* __restrict__ pre) {
    __shared__ float tile[ROWS * KC];   // 32768 B
    const int tid  = threadIdx.x;
    const int row0 = blockIdx.x * ROWS;
    const int srow = tid >> 3;          // 0..31 (row within each 32-row group)
    const int sk4  = tid & 7;           // float4 index within a 32-float chunk

    const float* cvec = wsf + 8448;
    float acc[32];
#pragma unroll
    for (int k = 0; k < 32; k++) acc[k] = cvec[k];

    // Coalesced assignment: iteration it covers rows it*32 + srow.
    // One wave = 8 rows x 8 float4 = 8 fully-used 128B lines per instruction.
    const float* xbase = x + (size_t)(row0 + srow) * IND + sk4 * 4;

    float4 R[8];
#pragma unroll
    for (int it = 0; it < 8; it++)
        R[it] = *(const float4*)(xbase + (size_t)it * 32 * IND);

#pragma unroll 1
    for (int c = 0; c < NCH; c++) {
        // R holds chunk c (issued last iteration, flew under last compute)
        asm volatile("s_waitcnt vmcnt(0)" ::: "memory");
        // scatter to LDS with rotation swizzle
#pragma unroll
        for (int it = 0; it < 8; it++) {
            float* trow = tile + (it * 32 + srow) * KC;
            const int k0 = sk4 * 4;
            trow[(k0 + 0 + srow) & 31] = R[it].x;
            trow[(k0 + 1 + srow) & 31] = R[it].y;
            trow[(k0 + 2 + srow) & 31] = R[it].z;
            trow[(k0 + 3 + srow) & 31] = R[it].w;
        }
        // issue next chunk NOW; these stay in flight across the raw barrier
        // and land during the FMA phase below (no vmcnt drain at s_barrier)
        if (c + 1 < NCH) {
#pragma unroll
            for (int it = 0; it < 8; it++)
                R[it] = *(const float4*)(xbase + (c + 1) * KC + (size_t)it * 32 * IND);
        }
        asm volatile("s_waitcnt lgkmcnt(0)" ::: "memory");  // ds_writes visible
        __builtin_amdgcn_s_barrier();                       // tile ready
        const float* xr = tile + tid * KC;
        const float* wb = wsf + c * KC * 32;   // uniform -> scalar loads
#pragma unroll
        for (int k = 0; k < KC; k++) {
            float xk = xr[(k + tid) & 31];
            const float* wr = wb + k * 32;
#pragma unroll
            for (int kk = 0; kk < 32; kk++) acc[kk] = fmaf(xk, wr[kk], acc[kk]);
        }
        asm volatile("" ::: "memory");
        __builtin_amdgcn_s_barrier();   // readers done -> tile reusable
    }

    const int bt = row0 + tid;
    const int b = bt >> 9, t = bt & 511, t4 = t >> 2, tm = t & 3;
    float* dst = pre + ((size_t)(b * 128 + t4)) * 128 + tm;
#pragma unroll
    for (int k = 0; k < 32; k++) dst[k * 4] = acc[k];
}

#define SWZ(x, imm) __int_as_float(__builtin_amdgcn_ds_swizzle(__float_as_int(x), (imm)))

template <int CTRL>
__device__ __forceinline__ float dpp_shr(float x) {
    // row_shr within 16-lane rows; OOB lanes get 0 (guarded by caller).
    return __int_as_float(__builtin_amdgcn_update_dpp(
        0, __float_as_int(x), CTRL, 0xF, 0xF, true));
}

__global__ __launch_bounds__(64) void recur(const float* __restrict__ wsf,
                                            float* __restrict__ out) {
    const int lane = threadIdx.x;        // 0..63 (one wave)
    const int l32  = lane & 31;          // lane within 32-lane batch group
    const int half = lane >> 5;
    const int b    = blockIdx.x * 2 + half;
    const int g    = l32 >> 3;           // gate 0..3 (f,i,g,o)
    const int n    = l32 & 7;            // qubit / hidden index

    float whr[8];
#pragma unroll
    for (int j = 0; j < 8; j++) whr[j] = wsf[8192 + l32 * 8 + j];

    const float4* pp = (const float4*)(wsf + PRE_OFF) + (size_t)b * 128 * 32 + l32;

    float hx[8];
#pragma unroll
    for (int j = 0; j < 8; j++) hx[j] = 0.0f;
    float cx = 0.0f;

    float4 bufA = pp[0];
    float4 bufB = pp[32];

    float* outp = out + (size_t)b * TT * 8 + n;
    const float L2E = 1.4426950408889634f;

    for (int t4 = 0; t4 < 128; t4++) {
        float4 cur = (t4 & 1) ? bufB : bufA;
        int nx = (t4 + 2 < 128) ? (t4 + 2) : 127;
        if (t4 & 1) bufB = pp[(size_t)nx * 32];
        else        bufA = pp[(size_t)nx * 32];
        float pv4[4] = {cur.x, cur.y, cur.z, cur.w};
#pragma unroll
        for (int tm = 0; tm < 4; tm++) {
            float ang = pv4[tm];
#pragma unroll
            for (int j = 0; j < 8; j++) ang = fmaf(whr[j], hx[j], ang);
            float c = __cosf(ang);
            // inclusive prefix product of e (c with lane n==0 replaced by 1)
            float s = (n == 0) ? 1.0f : c;
            { float v = dpp_shr<0x111>(s); s = (n >= 1) ? s * v : s; }
            { float v = dpp_shr<0x112>(s); s = (n >= 2) ? s * v : s; }
            { float v = dpp_shr<0x114>(s); s = (n >= 4) ? s * v : s; }
            float c0 = SWZ(c, 0x018);   // cos of qubit 0 within this gate group
            float s7 = SWZ(s, 0x0F8);   // prod_{1..7}
            float m  = (n == 0) ? s7 : c0 * s;
            // f,i,o: sigmoid(m); g: tanh(m) = 2*sigmoid(2m)-1
            float kk  = (g == 2) ? (-2.0f * L2E) : (-L2E);
            float u   = __builtin_amdgcn_rcpf(1.0f + __builtin_amdgcn_exp2f(m * kk));
            float val = (g == 2) ? fmaf(2.0f, u, -1.0f) : u;
            float fv = SWZ(val, 0x007);
            float iv = SWZ(val, 0x107);
            float gv = SWZ(val, 0x207);
            float ov = SWZ(val, 0x307);
            cx = fmaf(fv, cx, iv * gv);
            float t2 = __builtin_amdgcn_exp2f(cx * (-2.0f * L2E));
            float th = fmaf(2.0f, __builtin_amdgcn_rcpf(1.0f + t2), -1.0f);
            float hxn = ov * th;
            if (l32 < 8) outp[(t4 * 4 + tm) * 8] = hxn;
            // broadcast new hx[0..7] to every lane (from own gate group's copies)
            hx[0] = SWZ(hxn, 0x018);
            hx[1] = SWZ(hxn, 0x038);
            hx[2] = SWZ(hxn, 0x058);
            hx[3] = SWZ(hxn, 0x078);
            hx[4] = SWZ(hxn, 0x098);
            hx[5] = SWZ(hxn, 0x0B8);
            hx[6] = SWZ(hxn, 0x0D8);
            hx[7] = SWZ(hxn, 0x0F8);
        }
    }
    if (l32 < 8) {
        out[(size_t)BQ * TT * 8 + b * 8 + n]            = hx[n];
        out[(size_t)BQ * TT * 8 + BQ * 8 + b * 8 + n]   = cx;
    }
}

extern "C" void kernel_launch(void* const* d_in, const int* in_sizes, int n_in,
                              void* d_out, int out_size, void* d_ws, size_t ws_size,
                              hipStream_t stream) {
    const float* x  = (const float*)d_in[0];
    const float* Wf = (const float*)d_in[1];
    const float* bf = (const float*)d_in[2];
    const float* Wi = (const float*)d_in[3];
    const float* bi = (const float*)d_in[4];
    const float* Wg = (const float*)d_in[5];
    const float* bg = (const float*)d_in[6];
    const float* Wo = (const float*)d_in[7];
    const float* bo = (const float*)d_in[8];
    const float* th = (const float*)d_in[9];
    float* wsf = (float*)d_ws;
    float* out = (float*)d_out;

    prep_kernel<<<1, 256, 0, stream>>>(Wf, bf, Wi, bi, Wg, bg, Wo, bo, th, wsf);
    pre_gemm<<<(BQ * TT) / 256, 256, 0, stream>>>(x, wsf, wsf + PRE_OFF);
    recur<<<BQ / 2, 64, 0, stream>>>(wsf, out);
}